// Round 4
// baseline (574.369 us; speedup 1.0000x reference)
//
#include <hip/hip_runtime.h>

#define HDIM 1024
#define TLEN 2048
#define NBATCH 16

typedef short bf16x8 __attribute__((ext_vector_type(8)));
typedef float floatx4 __attribute__((ext_vector_type(4)));
typedef unsigned short ushort_t;

__device__ __forceinline__ ushort_t f2bf(float x) {
  unsigned u = __float_as_uint(x);
  unsigned r = (u + 0x7FFFu + ((u >> 16) & 1u)) >> 16;
  return (ushort_t)r;
}
__device__ __forceinline__ float bf2f(ushort_t h) {
  return __uint_as_float(((unsigned)h) << 16);
}

#define LSTR 40     // staged slab row stride (32 + 8 pad) in bf16 elems
#define TSTR 71     // prep transpose stride (64x64 tiles)
#define TSTR2 136   // sq epilogue transpose stride (128x128 tiles, 16B-aligned rows)

// ---------------- prep: split A into bf16 h/m/l (+transposed); init V col0 / U row0 ----------------
__global__ __launch_bounds__(256) void prep(const float* __restrict__ A,
    const float* __restrict__ Bv, const float* __restrict__ Cv,
    ushort_t* __restrict__ Ah, ushort_t* __restrict__ Am, ushort_t* __restrict__ Al,
    ushort_t* __restrict__ ATh, ushort_t* __restrict__ ATm, ushort_t* __restrict__ ATl,
    float* __restrict__ Vc, float* __restrict__ U) {
  __shared__ ushort_t Lt[3 * 64 * TSTR];
  const int tid = threadIdx.x;
  if (blockIdx.x >= 256) {  // init blocks
    int i = (blockIdx.x - 256) * 256 + tid;
    if (i < HDIM) Vc[i] = Bv[i];
    else U[i - HDIM] = Cv[i - HDIM];
    return;
  }
  const int row0 = (blockIdx.x >> 4) * 64, col0 = (blockIdx.x & 15) * 64;
  const int r = tid >> 2, q = tid & 3;
  ushort_t hs[16], ms[16], ls[16];
#pragma unroll
  for (int c4 = 0; c4 < 4; ++c4) {
    float4 a = *(const float4*)&A[(row0 + r) * HDIM + col0 + q * 16 + c4 * 4];
    float av[4] = {a.x, a.y, a.z, a.w};
#pragma unroll
    for (int i = 0; i < 4; ++i) {
      float z = av[i];
      ushort_t h = f2bf(z); float r1 = z - bf2f(h);
      ushort_t mq = f2bf(r1); float r2 = r1 - bf2f(mq);
      ushort_t lq = f2bf(r2);
      hs[c4 * 4 + i] = h; ms[c4 * 4 + i] = mq; ls[c4 * 4 + i] = lq;
    }
  }
  size_t go = (size_t)(row0 + r) * HDIM + col0 + q * 16;
  *(uint4*)&Ah[go] = ((uint4*)hs)[0]; *(uint4*)&Ah[go + 8] = ((uint4*)hs)[1];
  *(uint4*)&Am[go] = ((uint4*)ms)[0]; *(uint4*)&Am[go + 8] = ((uint4*)ms)[1];
  *(uint4*)&Al[go] = ((uint4*)ls)[0]; *(uint4*)&Al[go + 8] = ((uint4*)ls)[1];
#pragma unroll
  for (int i = 0; i < 16; ++i) {
    int c = q * 16 + i;
    Lt[0 * 64 * TSTR + r * TSTR + c] = hs[i];
    Lt[1 * 64 * TSTR + r * TSTR + c] = ms[i];
    Lt[2 * 64 * TSTR + r * TSTR + c] = ls[i];
  }
  __syncthreads();
  const int c = tid >> 2, q2 = tid & 3;
  ushort_t* dsts[3] = {ATh, ATm, ATl};
#pragma unroll
  for (int s = 0; s < 3; ++s) {
    ushort_t tmp[16];
#pragma unroll
    for (int rr = 0; rr < 16; ++rr) tmp[rr] = Lt[s * 64 * TSTR + (q2 * 16 + rr) * TSTR + c];
    size_t gt = (size_t)(col0 + c) * HDIM + row0 + q2 * 16;
    *(uint4*)&dsts[s][gt] = ((uint4*)tmp)[0];
    *(uint4*)&dsts[s][gt + 8] = ((uint4*)tmp)[1];
  }
}

// ---------------- Z = X*X, 128x128 tiles, bf16 split MFMA + fused V/U tail ----------------
// SIX: 6 cross terms (needs l splits of input) else 4 terms (h/m only)
// WRITEL: emit l splits of output (needed iff next stage is SIX)
// MODE 0: tail: V col1 = A*Bv (fp32);  MODE 1: V cols NC..2NC-1 = P*V[0:NC]
// MODE 2: U rows NC..2NC-1 = U[0:NC]*P (via transposed splits)
template <int MODE, int NC, bool SIX, bool WRITEL>
__global__ __launch_bounds__(256) void sq_mfma(
    const ushort_t* __restrict__ Xh, const ushort_t* __restrict__ Xm,
    const ushort_t* __restrict__ Xl,
    const ushort_t* __restrict__ XTh, const ushort_t* __restrict__ XTm,
    const ushort_t* __restrict__ XTl,
    ushort_t* __restrict__ Zh, ushort_t* __restrict__ Zm, ushort_t* __restrict__ Zl,
    ushort_t* __restrict__ ZTh, ushort_t* __restrict__ ZTm, ushort_t* __restrict__ ZTl,
    const float* __restrict__ Af, const float* __restrict__ Bvf,
    float* __restrict__ VU) {
  __shared__ ushort_t sm[6 * 128 * LSTR];  // 61440 B; epilogue reuses as transpose buf
  const int tid = threadIdx.x;

  if (blockIdx.x >= 64) {  // ---- tail blocks: 256 blocks -> 1024 waves ----
    const int tb = blockIdx.x - 64;
    const int wv = tb * 4 + (tid >> 6);
    const int lane = tid & 63;
    if (MODE == 0) {
      float acc = 0.f;
      for (int k = lane; k < HDIM; k += 64) acc += Af[(size_t)wv * HDIM + k] * Bvf[k];
      for (int off = 32; off; off >>= 1) acc += __shfl_down(acc, off);
      if (lane == 0) VU[HDIM + wv] = acc;
    } else {
      const ushort_t* Ph = (MODE == 1) ? Xh : XTh;
      const ushort_t* Pm = (MODE == 1) ? Xm : XTm;
      float acc[NC];
#pragma unroll
      for (int n = 0; n < NC; ++n) acc[n] = 0.f;
      for (int k = lane; k < HDIM; k += 64) {
        float a = bf2f(Ph[(size_t)wv * HDIM + k]) + bf2f(Pm[(size_t)wv * HDIM + k]);
#pragma unroll
        for (int n = 0; n < NC; ++n) acc[n] += a * VU[(size_t)n * HDIM + k];
      }
#pragma unroll
      for (int n = 0; n < NC; ++n) {
        float s = acc[n];
        for (int off = 32; off; off >>= 1) s += __shfl_down(s, off);
        if (lane == 0) VU[(size_t)(NC + n) * HDIM + wv] = s;
      }
    }
    return;
  }

  // ---- squaring blocks: 8x8 grid of 128x128 tiles ----
  const int AH = 0, AM = 128 * LSTR, AL = 2 * 128 * LSTR;
  const int BH = 3 * 128 * LSTR, BM = 4 * 128 * LSTR, BL = 5 * 128 * LSTR;
  const int w = tid >> 6, l = tid & 63, li = l & 15, quad = l >> 4;
  const int wr = w >> 1, wc = w & 1;             // 2x2 waves, each 64x64
  const int row0 = (blockIdx.x & 7) * 128, col0 = (blockIdx.x >> 3) * 128;
  const int sr = tid >> 1, sh = (tid & 1) * 16;  // staging: row sr, 16-elem half sh

  floatx4 acc[4][4];
#pragma unroll
  for (int i = 0; i < 4; ++i)
#pragma unroll
    for (int j = 0; j < 4; ++j) acc[i][j] = (floatx4){0.f, 0.f, 0.f, 0.f};

  const int soff = sr * LSTR + sh;
  const size_t gA = (size_t)(row0 + sr) * HDIM + sh;
  const size_t gB = (size_t)(col0 + sr) * HDIM + sh;

  uint4 pah0 = *(const uint4*)&Xh[gA], pah1 = *(const uint4*)&Xh[gA + 8];
  uint4 pam0 = *(const uint4*)&Xm[gA], pam1 = *(const uint4*)&Xm[gA + 8];
  uint4 pbh0 = *(const uint4*)&XTh[gB], pbh1 = *(const uint4*)&XTh[gB + 8];
  uint4 pbm0 = *(const uint4*)&XTm[gB], pbm1 = *(const uint4*)&XTm[gB + 8];
  uint4 pal0, pal1, pbl0, pbl1;
  if (SIX) {
    pal0 = *(const uint4*)&Xl[gA]; pal1 = *(const uint4*)&Xl[gA + 8];
    pbl0 = *(const uint4*)&XTl[gB]; pbl1 = *(const uint4*)&XTl[gB + 8];
  }

  for (int k0 = 0; k0 < HDIM; k0 += 32) {
    __syncthreads();
    *(uint4*)&sm[AH + soff] = pah0; *(uint4*)&sm[AH + soff + 8] = pah1;
    *(uint4*)&sm[AM + soff] = pam0; *(uint4*)&sm[AM + soff + 8] = pam1;
    *(uint4*)&sm[BH + soff] = pbh0; *(uint4*)&sm[BH + soff + 8] = pbh1;
    *(uint4*)&sm[BM + soff] = pbm0; *(uint4*)&sm[BM + soff + 8] = pbm1;
    if (SIX) {
      *(uint4*)&sm[AL + soff] = pal0; *(uint4*)&sm[AL + soff + 8] = pal1;
      *(uint4*)&sm[BL + soff] = pbl0; *(uint4*)&sm[BL + soff + 8] = pbl1;
    }
    __syncthreads();
    if (k0 + 32 < HDIM) {
      pah0 = *(const uint4*)&Xh[gA + k0 + 32]; pah1 = *(const uint4*)&Xh[gA + k0 + 40];
      pam0 = *(const uint4*)&Xm[gA + k0 + 32]; pam1 = *(const uint4*)&Xm[gA + k0 + 40];
      pbh0 = *(const uint4*)&XTh[gB + k0 + 32]; pbh1 = *(const uint4*)&XTh[gB + k0 + 40];
      pbm0 = *(const uint4*)&XTm[gB + k0 + 32]; pbm1 = *(const uint4*)&XTm[gB + k0 + 40];
      if (SIX) {
        pal0 = *(const uint4*)&Xl[gA + k0 + 32]; pal1 = *(const uint4*)&Xl[gA + k0 + 40];
        pbl0 = *(const uint4*)&XTl[gB + k0 + 32]; pbl1 = *(const uint4*)&XTl[gB + k0 + 40];
      }
    }
    bf16x8 ah[4], am[4], al[4];
#pragma unroll
    for (int ri = 0; ri < 4; ++ri) {
      int ao = (wr * 64 + ri * 16 + li) * LSTR + quad * 8;
      ah[ri] = *(const bf16x8*)&sm[AH + ao];
      am[ri] = *(const bf16x8*)&sm[AM + ao];
      if (SIX) al[ri] = *(const bf16x8*)&sm[AL + ao];
    }
#pragma unroll
    for (int cj = 0; cj < 4; ++cj) {
      int bo = (wc * 64 + cj * 16 + li) * LSTR + quad * 8;
      bf16x8 bh = *(const bf16x8*)&sm[BH + bo];
      bf16x8 bm = *(const bf16x8*)&sm[BM + bo];
      bf16x8 bl;
      if (SIX) bl = *(const bf16x8*)&sm[BL + bo];
#pragma unroll
      for (int ri = 0; ri < 4; ++ri) {
        floatx4 a = acc[ri][cj];
        a = __builtin_amdgcn_mfma_f32_16x16x32_bf16(ah[ri], bh, a, 0, 0, 0);
        a = __builtin_amdgcn_mfma_f32_16x16x32_bf16(ah[ri], bm, a, 0, 0, 0);
        a = __builtin_amdgcn_mfma_f32_16x16x32_bf16(am[ri], bh, a, 0, 0, 0);
        a = __builtin_amdgcn_mfma_f32_16x16x32_bf16(am[ri], bm, a, 0, 0, 0);
        if (SIX) {
          a = __builtin_amdgcn_mfma_f32_16x16x32_bf16(ah[ri], bl, a, 0, 0, 0);
          a = __builtin_amdgcn_mfma_f32_16x16x32_bf16(al[ri], bh, a, 0, 0, 0);
        }
        acc[ri][cj] = a;
      }
    }
  }

  // ---- epilogue ----
  // (1) row-major splits: direct scalar stores
#pragma unroll
  for (int ri = 0; ri < 4; ++ri)
#pragma unroll
    for (int cj = 0; cj < 4; ++cj)
#pragma unroll
      for (int e = 0; e < 4; ++e) {
        float z = acc[ri][cj][e];
        int rl = wr * 64 + ri * 16 + quad * 4 + e;
        int cl = wc * 64 + cj * 16 + li;
        size_t go = (size_t)(row0 + rl) * HDIM + col0 + cl;
        ushort_t h = f2bf(z); float r1 = z - bf2f(h);
        ushort_t mq = f2bf(r1);
        Zh[go] = h; Zm[go] = mq;
        if (WRITEL) { float r2 = r1 - bf2f(mq); Zl[go] = f2bf(r2); }
      }
  // (2) transposed splits via LDS (one pass per split)
  const int npass = WRITEL ? 3 : 2;
  ushort_t* dsts[3] = {ZTh, ZTm, ZTl};
  for (int p = 0; p < npass; ++p) {
    __syncthreads();
#pragma unroll
    for (int ri = 0; ri < 4; ++ri)
#pragma unroll
      for (int cj = 0; cj < 4; ++cj)
#pragma unroll
        for (int e = 0; e < 4; ++e) {
          float z = acc[ri][cj][e];
          int rl = wr * 64 + ri * 16 + quad * 4 + e;
          int cl = wc * 64 + cj * 16 + li;
          ushort_t h = f2bf(z);
          ushort_t v;
          if (p == 0) v = h;
          else {
            float r1 = z - bf2f(h);
            ushort_t mq = f2bf(r1);
            if (p == 1) v = mq;
            else v = f2bf(r1 - bf2f(mq));
          }
          sm[cl * TSTR2 + rl] = v;  // store transposed
        }
    __syncthreads();
    // vector out: thread t -> XT row (col0+c), 64 row-elems
    const int c = tid >> 1, seg = (tid & 1) * 64;
    ushort_t* dst = dsts[p];
#pragma unroll
    for (int i = 0; i < 8; ++i) {
      uint4 v = *(const uint4*)&sm[c * TSTR2 + seg + i * 8];
      *(uint4*)&dst[(size_t)(col0 + c) * HDIM + row0 + seg + i * 8] = v;
    }
  }
}

// ---------------- U extension: rows dst..dst+7 = rows dst-8..dst-1 x A^512 ----------------
__global__ __launch_bounds__(256) void utail8(const ushort_t* __restrict__ PTh,
                                              const ushort_t* __restrict__ PTm,
                                              float* __restrict__ U, int dstbase) {
  const int wv = blockIdx.x * 4 + (threadIdx.x >> 6);
  const int lane = threadIdx.x & 63;
  float acc[8];
#pragma unroll
  for (int m = 0; m < 8; ++m) acc[m] = 0.f;
  const float* Usrc = U + (size_t)(dstbase - 8) * HDIM;
  for (int k = lane; k < HDIM; k += 64) {
    float a = bf2f(PTh[(size_t)wv * HDIM + k]) + bf2f(PTm[(size_t)wv * HDIM + k]);
#pragma unroll
    for (int m = 0; m < 8; ++m) acc[m] += a * Usrc[(size_t)m * HDIM + k];
  }
#pragma unroll
  for (int m = 0; m < 8; ++m) {
    float s = acc[m];
    for (int off = 32; off; off >>= 1) s += __shfl_down(s, off);
    if (lane == 0) U[(size_t)(dstbase + m) * HDIM + wv] = s;
  }
}

// ---------------- K[m] = U row (m>>6) . V col (m&63) ----------------
__global__ __launch_bounds__(256) void wavedotK(const float* __restrict__ U,
                                                const float* __restrict__ Vc,
                                                float* __restrict__ Km) {
  int wv = (blockIdx.x * blockDim.x + threadIdx.x) >> 6;
  int lane = threadIdx.x & 63;
  if (wv >= 32 * 64) return;
  int mr = wv >> 6;
  int nc = wv & 63;
  float s = 0.f;
  for (int k = lane; k < HDIM; k += 64) s += U[mr * HDIM + k] * Vc[nc * HDIM + k];
  for (int off = 32; off; off >>= 1) s += __shfl_down(s, off);
  if (lane == 0) Km[wv] = s;
}

// ---------------- causal conv, LDS-tiled ----------------
__global__ __launch_bounds__(256) void convk2(const float* __restrict__ u,
                                              const float* __restrict__ Km,
                                              const float* __restrict__ Dv,
                                              float* __restrict__ y) {
  __shared__ float ks[256];
  __shared__ float us[512];
  const int tt = threadIdx.x;
  const int t0 = blockIdx.x * 256;
  const int b = blockIdx.y;
  const float* ub = u + (size_t)b * TLEN;
  const int t = t0 + tt;
  float s = Dv[0] * ub[t];
  for (int mc = 0; mc <= t0; mc += 256) {
    __syncthreads();
    ks[tt] = Km[mc + tt];
    int w0 = t0 - mc - 255;
    int g0 = w0 + tt;
    us[tt] = (g0 >= 0) ? ub[g0] : 0.f;
    int g1 = w0 + 256 + tt;
    us[256 + tt] = (g1 < TLEN) ? ub[g1] : 0.f;
    __syncthreads();
    if (mc < t0) {
#pragma unroll 4
      for (int r = 0; r < 256; r += 4) {
        float4 kv = *(const float4*)&ks[r];
        s += kv.x * us[tt - r + 255];
        s += kv.y * us[tt - r + 254];
        s += kv.z * us[tt - r + 253];
        s += kv.w * us[tt - r + 252];
      }
    } else {
      for (int r = 0; r <= tt; ++r) s += ks[r] * us[tt - r + 255];
    }
  }
  y[(size_t)b * TLEN + t] = s;
}

extern "C" void kernel_launch(void* const* d_in, const int* in_sizes, int n_in,
                              void* d_out, int out_size, void* d_ws, size_t ws_size,
                              hipStream_t stream) {
  const float* u  = (const float*)d_in[0];
  const float* A  = (const float*)d_in[1];
  const float* Bv = (const float*)d_in[2];
  const float* Cv = (const float*)d_in[3];
  const float* Dv = (const float*)d_in[4];
  float* out = (float*)d_out;

  char* wsb = (char*)d_ws;
  size_t off = 0;
  ushort_t* S[2][6];
  for (int s = 0; s < 2; ++s)
    for (int a = 0; a < 6; ++a) { S[s][a] = (ushort_t*)(wsb + off); off += (size_t)2 << 20; }
  float* Vc = (float*)(wsb + off); off += 64 * HDIM * 4;
  float* U  = (float*)(wsb + off); off += 32 * HDIM * 4;
  float* Km = (float*)(wsb + off); off += TLEN * 4;

  const dim3 gsq(320);  // 64 squaring blocks + 256 tail blocks

#define SQ(MODE, NC, SIX, WRL, IN, OUT, VU)                                    \
  sq_mfma<MODE, NC, SIX, WRL><<<gsq, 256, 0, stream>>>(                        \
      S[IN][0], S[IN][1], S[IN][2], S[IN][3], S[IN][4], S[IN][5],              \
      S[OUT][0], S[OUT][1], S[OUT][2], S[OUT][3], S[OUT][4], S[OUT][5],        \
      A, Bv, VU)

  prep<<<dim3(264), 256, 0, stream>>>(A, Bv, Cv,
      S[0][0], S[0][1], S[0][2], S[0][3], S[0][4], S[0][5], Vc, U);

  SQ(0, 1,  true,  true,  0, 1, Vc);  // A^2    ; tail: V col1 = A*Bv
  SQ(1, 2,  true,  true,  1, 0, Vc);  // A^4    ; tail: V cols 2,3    (A^2)
  SQ(1, 4,  true,  true,  0, 1, Vc);  // A^8    ; tail: V cols 4..7   (A^4)
  SQ(1, 8,  true,  false, 1, 0, Vc);  // A^16   ; tail: V cols 8..15  (A^8)
  SQ(1, 16, false, false, 0, 1, Vc);  // A^32   ; tail: V cols 16..31 (A^16)
  SQ(1, 32, false, false, 1, 0, Vc);  // A^64   ; tail: V cols 32..63 (A^32)
  SQ(2, 1,  false, false, 0, 1, U);   // A^128  ; tail: U row 1       (A^64)
  SQ(2, 2,  false, false, 1, 0, U);   // A^256  ; tail: U rows 2,3    (A^128)
  SQ(2, 4,  false, false, 0, 1, U);   // A^512  ; tail: U rows 4..7   (A^256)
#undef SQ

  // U rows 8..31 via A^512 (in S[1], transposed splits at idx 3,4), sequential x3
  utail8<<<dim3(256), 256, 0, stream>>>(S[1][3], S[1][4], U, 8);
  utail8<<<dim3(256), 256, 0, stream>>>(S[1][3], S[1][4], U, 16);
  utail8<<<dim3(256), 256, 0, stream>>>(S[1][3], S[1][4], U, 24);

  wavedotK<<<dim3(512), 256, 0, stream>>>(U, Vc, Km);
  convk2<<<dim3(TLEN / 256, NBATCH), 256, 0, stream>>>(u, Km, Dv, out);
}

// Round 5
// 333.442 us; speedup vs baseline: 1.7225x; 1.7225x over previous
//
#include <hip/hip_runtime.h>

#define HDIM 1024
#define TLEN 2048
#define NBATCH 16

typedef short bf16x8 __attribute__((ext_vector_type(8)));
typedef float floatx4 __attribute__((ext_vector_type(4)));
typedef unsigned short ushort_t;

__device__ __forceinline__ ushort_t f2bf(float x) {
  unsigned u = __float_as_uint(x);
  unsigned r = (u + 0x7FFFu + ((u >> 16) & 1u)) >> 16;
  return (ushort_t)r;
}
__device__ __forceinline__ float bf2f(ushort_t h) {
  return __uint_as_float(((unsigned)h) << 16);
}

#define LSTR 40     // staged slab row stride (32 + 8 pad) in bf16 elems
#define TSTR 71     // epilogue/prep transpose stride (64x64 tiles)

// ---------------- prep: split A into bf16 h/m/l (+transposed); init V col0 / U row0 ----------------
__global__ __launch_bounds__(256) void prep(const float* __restrict__ A,
    const float* __restrict__ Bv, const float* __restrict__ Cv,
    ushort_t* __restrict__ Ah, ushort_t* __restrict__ Am, ushort_t* __restrict__ Al,
    ushort_t* __restrict__ ATh, ushort_t* __restrict__ ATm, ushort_t* __restrict__ ATl,
    float* __restrict__ Vc, float* __restrict__ U) {
  __shared__ ushort_t Lt[3 * 64 * TSTR];
  const int tid = threadIdx.x;
  if (blockIdx.x >= 256) {  // init blocks
    int i = (blockIdx.x - 256) * 256 + tid;
    if (i < HDIM) Vc[i] = Bv[i];
    else U[i - HDIM] = Cv[i - HDIM];
    return;
  }
  const int row0 = (blockIdx.x >> 4) * 64, col0 = (blockIdx.x & 15) * 64;
  const int r = tid >> 2, q = tid & 3;
  ushort_t hs[16], ms[16], ls[16];
#pragma unroll
  for (int c4 = 0; c4 < 4; ++c4) {
    float4 a = *(const float4*)&A[(row0 + r) * HDIM + col0 + q * 16 + c4 * 4];
    float av[4] = {a.x, a.y, a.z, a.w};
#pragma unroll
    for (int i = 0; i < 4; ++i) {
      float z = av[i];
      ushort_t h = f2bf(z); float r1 = z - bf2f(h);
      ushort_t mq = f2bf(r1); float r2 = r1 - bf2f(mq);
      ushort_t lq = f2bf(r2);
      hs[c4 * 4 + i] = h; ms[c4 * 4 + i] = mq; ls[c4 * 4 + i] = lq;
    }
  }
  size_t go = (size_t)(row0 + r) * HDIM + col0 + q * 16;
  *(uint4*)&Ah[go] = ((uint4*)hs)[0]; *(uint4*)&Ah[go + 8] = ((uint4*)hs)[1];
  *(uint4*)&Am[go] = ((uint4*)ms)[0]; *(uint4*)&Am[go + 8] = ((uint4*)ms)[1];
  *(uint4*)&Al[go] = ((uint4*)ls)[0]; *(uint4*)&Al[go + 8] = ((uint4*)ls)[1];
#pragma unroll
  for (int i = 0; i < 16; ++i) {
    int c = q * 16 + i;
    Lt[0 * 64 * TSTR + r * TSTR + c] = hs[i];
    Lt[1 * 64 * TSTR + r * TSTR + c] = ms[i];
    Lt[2 * 64 * TSTR + r * TSTR + c] = ls[i];
  }
  __syncthreads();
  const int c = tid >> 2, q2 = tid & 3;
  ushort_t* dsts[3] = {ATh, ATm, ATl};
#pragma unroll
  for (int s = 0; s < 3; ++s) {
    ushort_t tmp[16];
#pragma unroll
    for (int rr = 0; rr < 16; ++rr) tmp[rr] = Lt[s * 64 * TSTR + (q2 * 16 + rr) * TSTR + c];
    size_t gt = (size_t)(col0 + c) * HDIM + row0 + q2 * 16;
    *(uint4*)&dsts[s][gt] = ((uint4*)tmp)[0];
    *(uint4*)&dsts[s][gt + 8] = ((uint4*)tmp)[1];
  }
}

// ---------------- Z = X*X, 64x64 tiles (256 blocks, XCD-swizzled) + fused V/U tail ----------------
// SIX: 6 cross terms (reads l splits) else 4 (h/m).  WRITEL: emit l splits of Z.
// MODE 0 tail: V col1 = A*Bv (fp32); MODE 1: V cols NC..2NC-1 = P*V[0:NC];
// MODE 2: U rows NC..2NC-1 = U[0:NC]*P (transposed splits).
template <int MODE, int NC, bool SIX, bool WRITEL>
__global__ __launch_bounds__(256) void sq_mfma(
    const ushort_t* __restrict__ Xh, const ushort_t* __restrict__ Xm,
    const ushort_t* __restrict__ Xl,
    const ushort_t* __restrict__ XTh, const ushort_t* __restrict__ XTm,
    const ushort_t* __restrict__ XTl,
    ushort_t* __restrict__ Zh, ushort_t* __restrict__ Zm, ushort_t* __restrict__ Zl,
    ushort_t* __restrict__ ZTh, ushort_t* __restrict__ ZTm, ushort_t* __restrict__ ZTl,
    const float* __restrict__ Af, const float* __restrict__ Bvf,
    float* __restrict__ VU) {
  __shared__ ushort_t sm[6 * 64 * LSTR];  // 30720 B; epilogue reuses as transpose buf
  const int tid = threadIdx.x;

  if (blockIdx.x >= 256) {  // ---- tail blocks: 256 blocks -> 1024 waves ----
    const int tb = blockIdx.x - 256;
    const int wv = tb * 4 + (tid >> 6);
    const int lane = tid & 63;
    if (MODE == 0) {
      float acc = 0.f;
      for (int k = lane; k < HDIM; k += 64) acc += Af[(size_t)wv * HDIM + k] * Bvf[k];
      for (int off = 32; off; off >>= 1) acc += __shfl_down(acc, off);
      if (lane == 0) VU[HDIM + wv] = acc;
    } else {
      const ushort_t* Ph = (MODE == 1) ? Xh : XTh;
      const ushort_t* Pm = (MODE == 1) ? Xm : XTm;
      float acc[NC];
#pragma unroll
      for (int n = 0; n < NC; ++n) acc[n] = 0.f;
      for (int k = lane; k < HDIM; k += 64) {
        float a = bf2f(Ph[(size_t)wv * HDIM + k]) + bf2f(Pm[(size_t)wv * HDIM + k]);
#pragma unroll
        for (int n = 0; n < NC; ++n) acc[n] += a * VU[(size_t)n * HDIM + k];
      }
#pragma unroll
      for (int n = 0; n < NC; ++n) {
        float s = acc[n];
        for (int off = 32; off; off >>= 1) s += __shfl_down(s, off);
        if (lane == 0) VU[(size_t)(NC + n) * HDIM + wv] = s;
      }
    }
    return;
  }

  // ---- squaring blocks: 16x16 grid of 64x64 tiles, XCD-rectangle swizzle ----
  // assume dispatch round-robins blockIdx%8 across XCDs: give each XCD a 4x8 tile rect
  const int bb = blockIdx.x;
  const int xcd = bb & 7, slot = bb >> 3;
  const int tr = 4 * (xcd >> 1) + (slot >> 3);
  const int tc = 8 * (xcd & 1) + (slot & 7);
  const int row0 = tr * 64, col0 = tc * 64;

  const int AH = 0, AM = 64 * LSTR, AL = 2 * 64 * LSTR;
  const int BH = 3 * 64 * LSTR, BM = 4 * 64 * LSTR, BL = 5 * 64 * LSTR;
  const int w = tid >> 6, l = tid & 63, li = l & 15, quad = l >> 4;
  const int sr = tid >> 2, sq4 = tid & 3;

  floatx4 acc0 = {0.f, 0.f, 0.f, 0.f}, acc1 = acc0, acc2 = acc0, acc3 = acc0;

  const int aoff = (w * 16 + li) * LSTR + quad * 8;
  const int b0o = (0 * 16 + li) * LSTR + quad * 8;
  const int b1o = (1 * 16 + li) * LSTR + quad * 8;
  const int b2o = (2 * 16 + li) * LSTR + quad * 8;
  const int b3o = (3 * 16 + li) * LSTR + quad * 8;
  const int soff = sr * LSTR + sq4 * 8;
  const size_t gA = (size_t)(row0 + sr) * HDIM + sq4 * 8;
  const size_t gB = (size_t)(col0 + sr) * HDIM + sq4 * 8;

  uint4 pa0 = *(const uint4*)&Xh[gA], pa1 = *(const uint4*)&Xm[gA];
  uint4 pb0 = *(const uint4*)&XTh[gB], pb1 = *(const uint4*)&XTm[gB];
  uint4 pa2, pb2;
  if (SIX) { pa2 = *(const uint4*)&Xl[gA]; pb2 = *(const uint4*)&XTl[gB]; }

  for (int k0 = 0; k0 < HDIM; k0 += 32) {
    __syncthreads();
    *(uint4*)&sm[AH + soff] = pa0;
    *(uint4*)&sm[AM + soff] = pa1;
    *(uint4*)&sm[BH + soff] = pb0;
    *(uint4*)&sm[BM + soff] = pb1;
    if (SIX) {
      *(uint4*)&sm[AL + soff] = pa2;
      *(uint4*)&sm[BL + soff] = pb2;
    }
    __syncthreads();
    if (k0 + 32 < HDIM) {
      pa0 = *(const uint4*)&Xh[gA + k0 + 32];
      pa1 = *(const uint4*)&Xm[gA + k0 + 32];
      pb0 = *(const uint4*)&XTh[gB + k0 + 32];
      pb1 = *(const uint4*)&XTm[gB + k0 + 32];
      if (SIX) {
        pa2 = *(const uint4*)&Xl[gA + k0 + 32];
        pb2 = *(const uint4*)&XTl[gB + k0 + 32];
      }
    }
    bf16x8 ah = *(const bf16x8*)&sm[AH + aoff];
    bf16x8 am = *(const bf16x8*)&sm[AM + aoff];
    bf16x8 al;
    if (SIX) al = *(const bf16x8*)&sm[AL + aoff];
    {
      bf16x8 bh = *(const bf16x8*)&sm[BH + b0o];
      bf16x8 bm = *(const bf16x8*)&sm[BM + b0o];
      acc0 = __builtin_amdgcn_mfma_f32_16x16x32_bf16(ah, bh, acc0, 0, 0, 0);
      acc0 = __builtin_amdgcn_mfma_f32_16x16x32_bf16(ah, bm, acc0, 0, 0, 0);
      acc0 = __builtin_amdgcn_mfma_f32_16x16x32_bf16(am, bh, acc0, 0, 0, 0);
      acc0 = __builtin_amdgcn_mfma_f32_16x16x32_bf16(am, bm, acc0, 0, 0, 0);
      if (SIX) {
        bf16x8 bl = *(const bf16x8*)&sm[BL + b0o];
        acc0 = __builtin_amdgcn_mfma_f32_16x16x32_bf16(ah, bl, acc0, 0, 0, 0);
        acc0 = __builtin_amdgcn_mfma_f32_16x16x32_bf16(al, bh, acc0, 0, 0, 0);
      }
    }
    {
      bf16x8 bh = *(const bf16x8*)&sm[BH + b1o];
      bf16x8 bm = *(const bf16x8*)&sm[BM + b1o];
      acc1 = __builtin_amdgcn_mfma_f32_16x16x32_bf16(ah, bh, acc1, 0, 0, 0);
      acc1 = __builtin_amdgcn_mfma_f32_16x16x32_bf16(ah, bm, acc1, 0, 0, 0);
      acc1 = __builtin_amdgcn_mfma_f32_16x16x32_bf16(am, bh, acc1, 0, 0, 0);
      acc1 = __builtin_amdgcn_mfma_f32_16x16x32_bf16(am, bm, acc1, 0, 0, 0);
      if (SIX) {
        bf16x8 bl = *(const bf16x8*)&sm[BL + b1o];
        acc1 = __builtin_amdgcn_mfma_f32_16x16x32_bf16(ah, bl, acc1, 0, 0, 0);
        acc1 = __builtin_amdgcn_mfma_f32_16x16x32_bf16(al, bh, acc1, 0, 0, 0);
      }
    }
    {
      bf16x8 bh = *(const bf16x8*)&sm[BH + b2o];
      bf16x8 bm = *(const bf16x8*)&sm[BM + b2o];
      acc2 = __builtin_amdgcn_mfma_f32_16x16x32_bf16(ah, bh, acc2, 0, 0, 0);
      acc2 = __builtin_amdgcn_mfma_f32_16x16x32_bf16(ah, bm, acc2, 0, 0, 0);
      acc2 = __builtin_amdgcn_mfma_f32_16x16x32_bf16(am, bh, acc2, 0, 0, 0);
      acc2 = __builtin_amdgcn_mfma_f32_16x16x32_bf16(am, bm, acc2, 0, 0, 0);
      if (SIX) {
        bf16x8 bl = *(const bf16x8*)&sm[BL + b2o];
        acc2 = __builtin_amdgcn_mfma_f32_16x16x32_bf16(ah, bl, acc2, 0, 0, 0);
        acc2 = __builtin_amdgcn_mfma_f32_16x16x32_bf16(al, bh, acc2, 0, 0, 0);
      }
    }
    {
      bf16x8 bh = *(const bf16x8*)&sm[BH + b3o];
      bf16x8 bm = *(const bf16x8*)&sm[BM + b3o];
      acc3 = __builtin_amdgcn_mfma_f32_16x16x32_bf16(ah, bh, acc3, 0, 0, 0);
      acc3 = __builtin_amdgcn_mfma_f32_16x16x32_bf16(ah, bm, acc3, 0, 0, 0);
      acc3 = __builtin_amdgcn_mfma_f32_16x16x32_bf16(am, bh, acc3, 0, 0, 0);
      acc3 = __builtin_amdgcn_mfma_f32_16x16x32_bf16(am, bm, acc3, 0, 0, 0);
      if (SIX) {
        bf16x8 bl = *(const bf16x8*)&sm[BL + b3o];
        acc3 = __builtin_amdgcn_mfma_f32_16x16x32_bf16(ah, bl, acc3, 0, 0, 0);
        acc3 = __builtin_amdgcn_mfma_f32_16x16x32_bf16(al, bh, acc3, 0, 0, 0);
      }
    }
  }

  // ---- epilogue: split, store row-major + LDS-transposed splits ----
  __syncthreads();
  floatx4 accs[4] = {acc0, acc1, acc2, acc3};
#pragma unroll
  for (int j = 0; j < 4; ++j) {
#pragma unroll
    for (int e = 0; e < 4; ++e) {
      float z = accs[j][e];
      int rl = w * 16 + quad * 4 + e;
      int cl = j * 16 + li;
      size_t go = (size_t)(row0 + rl) * HDIM + col0 + cl;
      ushort_t h = f2bf(z); float r1 = z - bf2f(h);
      ushort_t mq = f2bf(r1);
      Zh[go] = h; Zm[go] = mq;
      sm[0 * 64 * TSTR + rl * TSTR + cl] = h;
      sm[1 * 64 * TSTR + rl * TSTR + cl] = mq;
      if (WRITEL) {
        ushort_t lq = f2bf(r1 - bf2f(mq));
        Zl[go] = lq;
        sm[2 * 64 * TSTR + rl * TSTR + cl] = lq;
      }
    }
  }
  __syncthreads();
  const int c = tid >> 2, q2 = tid & 3;
  ushort_t* dsts[3] = {ZTh, ZTm, ZTl};
  const int npass = WRITEL ? 3 : 2;
#pragma unroll
  for (int s = 0; s < 3; ++s) {
    if (s >= npass) break;
    ushort_t tmp[16];
#pragma unroll
    for (int rr = 0; rr < 16; ++rr) tmp[rr] = sm[s * 64 * TSTR + (q2 * 16 + rr) * TSTR + c];
    size_t gt = (size_t)(col0 + c) * HDIM + row0 + q2 * 16;
    *(uint4*)&dsts[s][gt] = ((uint4*)tmp)[0];
    *(uint4*)&dsts[s][gt + 8] = ((uint4*)tmp)[1];
  }
}

// ---------------- U extension: rows dst..dst+7 = rows dst-8..dst-1 x A^512 ----------------
__global__ __launch_bounds__(256) void utail8(const ushort_t* __restrict__ PTh,
                                              const ushort_t* __restrict__ PTm,
                                              float* __restrict__ U, int dstbase) {
  const int wv = blockIdx.x * 4 + (threadIdx.x >> 6);
  const int lane = threadIdx.x & 63;
  float acc[8];
#pragma unroll
  for (int m = 0; m < 8; ++m) acc[m] = 0.f;
  const float* Usrc = U + (size_t)(dstbase - 8) * HDIM;
  for (int k = lane; k < HDIM; k += 64) {
    float a = bf2f(PTh[(size_t)wv * HDIM + k]) + bf2f(PTm[(size_t)wv * HDIM + k]);
#pragma unroll
    for (int m = 0; m < 8; ++m) acc[m] += a * Usrc[(size_t)m * HDIM + k];
  }
#pragma unroll
  for (int m = 0; m < 8; ++m) {
    float s = acc[m];
    for (int off = 32; off; off >>= 1) s += __shfl_down(s, off);
    if (lane == 0) U[(size_t)(dstbase + m) * HDIM + wv] = s;
  }
}

// ---------------- K[m] = U row (m>>6) . V col (m&63) ----------------
__global__ __launch_bounds__(256) void wavedotK(const float* __restrict__ U,
                                                const float* __restrict__ Vc,
                                                float* __restrict__ Km) {
  int wv = (blockIdx.x * blockDim.x + threadIdx.x) >> 6;
  int lane = threadIdx.x & 63;
  if (wv >= 32 * 64) return;
  int mr = wv >> 6;
  int nc = wv & 63;
  float s = 0.f;
  for (int k = lane; k < HDIM; k += 64) s += U[mr * HDIM + k] * Vc[nc * HDIM + k];
  for (int off = 32; off; off >>= 1) s += __shfl_down(s, off);
  if (lane == 0) Km[wv] = s;
}

// ---------------- causal conv, LDS-tiled ----------------
__global__ __launch_bounds__(256) void convk2(const float* __restrict__ u,
                                              const float* __restrict__ Km,
                                              const float* __restrict__ Dv,
                                              float* __restrict__ y) {
  __shared__ float ks[256];
  __shared__ float us[512];
  const int tt = threadIdx.x;
  const int t0 = blockIdx.x * 256;
  const int b = blockIdx.y;
  const float* ub = u + (size_t)b * TLEN;
  const int t = t0 + tt;
  float s = Dv[0] * ub[t];
  for (int mc = 0; mc <= t0; mc += 256) {
    __syncthreads();
    ks[tt] = Km[mc + tt];
    int w0 = t0 - mc - 255;
    int g0 = w0 + tt;
    us[tt] = (g0 >= 0) ? ub[g0] : 0.f;
    int g1 = w0 + 256 + tt;
    us[256 + tt] = (g1 < TLEN) ? ub[g1] : 0.f;
    __syncthreads();
    if (mc < t0) {
#pragma unroll 4
      for (int r = 0; r < 256; r += 4) {
        float4 kv = *(const float4*)&ks[r];
        s += kv.x * us[tt - r + 255];
        s += kv.y * us[tt - r + 254];
        s += kv.z * us[tt - r + 253];
        s += kv.w * us[tt - r + 252];
      }
    } else {
      for (int r = 0; r <= tt; ++r) s += ks[r] * us[tt - r + 255];
    }
  }
  y[(size_t)b * TLEN + t] = s;
}

extern "C" void kernel_launch(void* const* d_in, const int* in_sizes, int n_in,
                              void* d_out, int out_size, void* d_ws, size_t ws_size,
                              hipStream_t stream) {
  const float* u  = (const float*)d_in[0];
  const float* A  = (const float*)d_in[1];
  const float* Bv = (const float*)d_in[2];
  const float* Cv = (const float*)d_in[3];
  const float* Dv = (const float*)d_in[4];
  float* out = (float*)d_out;

  char* wsb = (char*)d_ws;
  size_t off = 0;
  ushort_t* S[2][6];
  for (int s = 0; s < 2; ++s)
    for (int a = 0; a < 6; ++a) { S[s][a] = (ushort_t*)(wsb + off); off += (size_t)2 << 20; }
  float* Vc = (float*)(wsb + off); off += 64 * HDIM * 4;
  float* U  = (float*)(wsb + off); off += 32 * HDIM * 4;
  float* Km = (float*)(wsb + off); off += TLEN * 4;

  const dim3 gsq(512);  // 256 squaring blocks (swizzled) + 256 tail blocks

#define SQ(MODE, NC, SIX, WRL, IN, OUT, VU)                                    \
  sq_mfma<MODE, NC, SIX, WRL><<<gsq, 256, 0, stream>>>(                        \
      S[IN][0], S[IN][1], S[IN][2], S[IN][3], S[IN][4], S[IN][5],              \
      S[OUT][0], S[OUT][1], S[OUT][2], S[OUT][3], S[OUT][4], S[OUT][5],        \
      A, Bv, VU)

  prep<<<dim3(264), 256, 0, stream>>>(A, Bv, Cv,
      S[0][0], S[0][1], S[0][2], S[0][3], S[0][4], S[0][5], Vc, U);

  SQ(0, 1,  true,  true,  0, 1, Vc);  // A^2    ; tail: V col1 = A*Bv
  SQ(1, 2,  true,  true,  1, 0, Vc);  // A^4    ; tail: V cols 2,3    (A^2)
  SQ(1, 4,  true,  true,  0, 1, Vc);  // A^8    ; tail: V cols 4..7   (A^4)
  SQ(1, 8,  true,  false, 1, 0, Vc);  // A^16   ; tail: V cols 8..15  (A^8)
  SQ(1, 16, false, false, 0, 1, Vc);  // A^32   ; tail: V cols 16..31 (A^16)
  SQ(1, 32, false, false, 1, 0, Vc);  // A^64   ; tail: V cols 32..63 (A^32)
  SQ(2, 1,  false, false, 0, 1, U);   // A^128  ; tail: U row 1       (A^64)
  SQ(2, 2,  false, false, 1, 0, U);   // A^256  ; tail: U rows 2,3    (A^128)
  SQ(2, 4,  false, false, 0, 1, U);   // A^512  ; tail: U rows 4..7   (A^256)
#undef SQ

  // U rows 8..31 via A^512 (S[1] transposed splits), sequential x3
  utail8<<<dim3(256), 256, 0, stream>>>(S[1][3], S[1][4], U, 8);
  utail8<<<dim3(256), 256, 0, stream>>>(S[1][3], S[1][4], U, 16);
  utail8<<<dim3(256), 256, 0, stream>>>(S[1][3], S[1][4], U, 24);

  wavedotK<<<dim3(512), 256, 0, stream>>>(U, Vc, Km);
  convk2<<<dim3(TLEN / 256, NBATCH), 256, 0, stream>>>(u, Km, Dv, out);
}